// Round 6
// baseline (306.482 us; speedup 1.0000x reference)
//
#include <hip/hip_runtime.h>
#include <cmath>
#include <complex>

namespace {

constexpr int TLEN   = 65536;
constexpr int NCH    = 512;            // 32*16 channels
constexpr size_t YB_ROWS = 16400;      // float4-groups in yb (valid g <= 16398)

// yb layout (round-0, proven): sample e at row s=e+5, float offset
// (s>>2)*2048 + ch*4 + (s&3). 1KB-contiguous per (group, 64ch tile).

struct Coefs {
  float b0,b1,b2,b3,b4,b5,b6,b7,b8;
  float na1,na2,na3,na4,na5,na6,na7,na8;   // -a[1..8]
  float zi0,zi1,zi2,zi3,zi4,zi5,zi6,zi7;
};

#define IIR_STEP(xv, yv)                                  \
  do {                                                    \
    yv = fmaf(cf.b0, (xv), z0);                           \
    z0 = fmaf(cf.na1, yv, fmaf(cf.b1, (xv), z1));         \
    z1 = fmaf(cf.na2, yv, fmaf(cf.b2, (xv), z2));         \
    z2 = fmaf(cf.na3, yv, fmaf(cf.b3, (xv), z3));         \
    z3 = fmaf(cf.na4, yv, fmaf(cf.b4, (xv), z4));         \
    z4 = fmaf(cf.na5, yv, fmaf(cf.b5, (xv), z5));         \
    z5 = fmaf(cf.na6, yv, fmaf(cf.b6, (xv), z6));         \
    z6 = fmaf(cf.na7, yv, fmaf(cf.b7, (xv), z7));         \
    z7 = fmaf(cf.na8, yv, cf.b8 * (xv));                  \
  } while (0)

// =============== K1: fused extension+transpose+forward scan ==================
// Round-4 structure (proven: FETCH=110MB WRITE=131MB, 112us): 4-wave blocks,
// wave 0 scans, all waves stage, 2-ring LDS (33.3KB -> 4 blocks/CU).
// Round-5 edit: chunk 128 merged into c=127 (nsub=13) -> grid exactly 1024
// blocks = one resident round, no straggler tail. VEC path gains a per-subtile
// interior test; only c=127 k=12 (and all of c=0) take the scalar mirror path.
template<int QOFF, bool VEC>
__device__ __forceinline__ void run_chunk(const float* __restrict__ x,
                                          float* __restrict__ yb,
                                          const Coefs& cf,
                                          float (&lds)[2][4160],
                                          int m0, int e0, int nsub,
                                          int store_lo, int store_hi) {
  const int tid  = threadIdx.x;
  const int lane = tid & 63;
  const int vtbase = e0 - 27;            // x-index of e0
  const int mIdx = m0 + lane;
  float4* yq = reinterpret_cast<float4*>(yb);
  const int tq  = tid & 15;              // VEC: float4-column within row
  const int chb = tid >> 4;              // VEC: base channel row (0..15)
  float4 rr0, rr1, rr2, rr3;             // VEC staging
  float rs[16];                          // edge staging

  auto interior = [&](int k) {
    const int vt0 = vtbase + 64 * k;
    return vt0 >= 0 && vt0 + 63 < TLEN;
  };
  auto issue = [&](int k) {
    const int vt0 = vtbase + 64 * k;
    if (VEC && interior(k)) {
      const float* p = x + (size_t)(m0 + chb) * TLEN + vt0 + 4 * tq;
      rr0 = *reinterpret_cast<const float4*>(p);
      rr1 = *reinterpret_cast<const float4*>(p + (size_t)16 * TLEN);
      rr2 = *reinterpret_cast<const float4*>(p + (size_t)32 * TLEN);
      rr3 = *reinterpret_cast<const float4*>(p + (size_t)48 * TLEN);
    } else {
#pragma unroll
      for (int i = 0; i < 16; ++i) {
        int idx = tid + 256 * i;
        int tl = idx & 63, ch = idx >> 6;
        int vt = vt0 + tl;
        const float* xr = x + (size_t)(m0 + ch) * TLEN;
        float v;
        if (vt < 0) v = 2.0f * xr[0] - xr[-vt];
        else if (vt >= TLEN) v = 2.0f * xr[TLEN - 1] - xr[2 * TLEN - 2 - vt];
        else v = xr[vt];
        rs[i] = v;
      }
    }
  };
  auto commit = [&](int k) {
    float* b = lds[k & 1];
    if (VEC && interior(k)) {
      const int base = 4 * tq * 65;
      b[base       + chb     ] = rr0.x; b[base + 65  + chb     ] = rr0.y;
      b[base + 130 + chb     ] = rr0.z; b[base + 195 + chb     ] = rr0.w;
      b[base       + chb + 16] = rr1.x; b[base + 65  + chb + 16] = rr1.y;
      b[base + 130 + chb + 16] = rr1.z; b[base + 195 + chb + 16] = rr1.w;
      b[base       + chb + 32] = rr2.x; b[base + 65  + chb + 32] = rr2.y;
      b[base + 130 + chb + 32] = rr2.z; b[base + 195 + chb + 32] = rr2.w;
      b[base       + chb + 48] = rr3.x; b[base + 65  + chb + 48] = rr3.y;
      b[base + 130 + chb + 48] = rr3.z; b[base + 195 + chb + 48] = rr3.w;
    } else {
#pragma unroll
      for (int i = 0; i < 16; ++i) {
        int idx = tid + 256 * i;
        int tl = idx & 63, ch = idx >> 6;
        b[tl * 65 + ch] = rs[i];
      }
    }
  };

  // prologue: subtile 0 only (2-ring, depth 1)
  issue(0); commit(0);

  float z0 = 0, z1 = 0, z2 = 0, z3 = 0, z4 = 0, z5 = 0, z6 = 0, z7 = 0;
  float4 oq = make_float4(0.f, 0.f, 0.f, 0.f);

  for (int k = 0; k < nsub; ++k) {
    if (k + 1 < nsub) issue(k + 1);      // loads in flight across the barrier
    __syncthreads();                     // buf k&1 committed (end of iter k-1)
    if (k == 0 && tid < 64) {
      float x0 = lds[0][lane];           // x_ext(e0)
      z0 = cf.zi0 * x0; z1 = cf.zi1 * x0; z2 = cf.zi2 * x0; z3 = cf.zi3 * x0;
      z4 = cf.zi4 * x0; z5 = cf.zi5 * x0; z6 = cf.zi6 * x0; z7 = cf.zi7 * x0;
    }
    if (tid < 64) {
      const float* tile = lds[k & 1];
#pragma unroll
      for (int tl = 0; tl < 64; ++tl) {
        float xin = tile[tl * 65 + lane];
        float yv; IIR_STEP(xin, yv);
        if (QOFF == 1) {                   // c==0 scalar head e=0,1,2 (grp1 q1..3)
          if (k == 0 && tl < 3) yb[2048 + mIdx * 4 + tl + 1] = yv;
        }
        const int q = (tl + QOFF) & 3;     // q = (e+1)&3, static after unroll
        if (q == 0) oq.x = yv;
        else if (q == 1) oq.y = yv;
        else if (q == 2) oq.z = yv;
        else {
          oq.w = yv;
          const int step = 64 * k + tl;
          if (step >= store_lo && step <= store_hi)
            yq[(size_t)((e0 + step + 5) >> 2) * 512 + mIdx] = oq;
        }
      }
    }
    if (k + 1 < nsub) commit(k + 1);     // writes buf (k+1)&1 (scan reads k&1)
  }
}

__global__ __launch_bounds__(256) void k_fwd2(const float* __restrict__ x,
                                              float* __restrict__ yb, Coefs cf) {
  __shared__ float lds[2][4160];           // 33.3 KB -> 4 blocks/CU
  const int c  = blockIdx.x;               // chunk 0..127
  const int m0 = blockIdx.y * 64;          // channel tile
  if (c == 0)
    run_chunk<1, false>(x, yb, cf, lds, m0, 0, 8, 6, 510);
  else if (c == 127)                       // merged tail: e 65026..65590 (row<=16398)
    run_chunk<0, true>(x, yb, cf, lds, m0, 512 * 127 - 253, 13, 255, 819);
  else
    run_chunk<0, true>(x, yb, cf, lds, m0, 512 * c - 253, 12, 255, 763);
}

// ---------------- K2: backward chunked scan -> out, fused transpose ----------
// Round-5: 128 chunks x 2 channel-halves = 256 blocks (exactly 1/CU at 143KB
// LDS). Chunk c owns out cols [128c, 128c+127] -> warm-up read factor drops
// 2.02x -> 1.51x (yb reads 270 -> 214 MB). Warm-up 272 steps (same margin as
// the passing round-4 kernel); c==127 takes the exact zi-init path. Depth-2
// in-register prefetch (b0..b11, 2 iterations ~720cyc) covers L3 latency at
// the reduced 4-waves/CU TLP. Packs staged as float4 in pitch-35 LDS
// (write banks: (12t+4cb)%32 -> 2-way free; read: sequential -> free), then
// out written in 512B-per-channel coalesced segments.
__global__ __launch_bounds__(256) void k_bwd3(const float* __restrict__ yb,
                                              float* __restrict__ out, Coefs cf) {
  __shared__ float4 wl4[256 * 35];       // [ch][32 col-quads], pitch 35 -> 143.4KB
  const int c   = blockIdx.x;            // 0..127
  const int tid = threadIdx.x;
  const int m   = blockIdx.y * 256 + tid;
  float z0, z1, z2, z3, z4, z5, z6, z7;
  int g_begin;
  if (c == 127) {                        // exact filtfilt backward init
    float y0 = yb[(size_t)16398 * 2048 + (size_t)m * 4 + 2];   // s=65594 (u=0)
    z0 = cf.zi0 * y0; z1 = cf.zi1 * y0; z2 = cf.zi2 * y0; z3 = cf.zi3 * y0;
    z4 = cf.zi4 * y0; z5 = cf.zi5 * y0; z6 = cf.zi6 * y0; z7 = cf.zi7 * y0;
#pragma unroll
    for (int s = 65594; s >= 65584; --s) {       // u = 0..10 (no owned outputs)
      float yin = yb[(size_t)(s >> 2) * 2048 + (size_t)m * 4 + (s & 3)];
      float wv; IIR_STEP(yin, wv);
      (void)wv;
    }
    g_begin = 16395;
  } else {
    g_begin = 128 * c + 203;                     // warm-up init at q3 of g_begin
    float y0 = yb[(size_t)g_begin * 2048 + (size_t)m * 4 + 3];
    z0 = cf.zi0 * y0; z1 = cf.zi1 * y0; z2 = cf.zi2 * y0; z3 = cf.zi3 * y0;
    z4 = cf.zi4 * y0; z5 = cf.zi5 * y0; z6 = cf.zi6 * y0; z7 = cf.zi7 * y0;
  }
  const int g_stop = 128 * c + 11;       // last pack: col-base 128c
  const int g_hi   = 128 * c + 135;      // first owned pack (c=127: 16391 too)
  const float4* yv = reinterpret_cast<const float4*>(yb);
  auto ld = [&](int r) {
    int rr = r < 0 ? 0 : r;
    return yv[(size_t)rr * 512 + m];
  };
  float4 b0 = ld(g_begin),     b1 = ld(g_begin - 1),  b2 = ld(g_begin - 2),  b3 = ld(g_begin - 3);
  float4 b4 = ld(g_begin - 4), b5 = ld(g_begin - 5),  b6 = ld(g_begin - 6),  b7 = ld(g_begin - 7);
  float4 b8 = ld(g_begin - 8), b9 = ld(g_begin - 9), b10 = ld(g_begin - 10), b11 = ld(g_begin - 11);
  for (int g = g_begin; g >= g_stop; g -= 4) {
    float4 c0 = b0, c1 = b1, c2 = b2, c3 = b3;
    b0 = b4; b1 = b5; b2 = b6;  b3 = b7;
    b4 = b8; b5 = b9; b6 = b10; b7 = b11;
    b8 = ld(g - 12); b9 = ld(g - 13); b10 = ld(g - 14); b11 = ld(g - 15);
    float4 pack;
#pragma unroll
    for (int j = 0; j < 4; ++j) {
      float4 q = (j == 0) ? c0 : (j == 1) ? c1 : (j == 2) ? c2 : c3;
      float w3, w2, w1, w0;
      IIR_STEP(q.w, w3);   // ascending u within group: q3,q2,q1,q0
      IIR_STEP(q.z, w2);
      IIR_STEP(q.y, w1);
      IIR_STEP(q.x, w0);
      (void)w3; (void)w2; (void)w1;
      if (j == 0) pack.w = w0;          // col g-8
      else if (j == 1) pack.z = w0;     // col g-9
      else if (j == 2) pack.y = w0;     // col g-10
      else pack.x = w0;                 // col g-11
    }
    if (g <= g_hi)                      // owned packs: col-base (g-11) in [128c, 128c+124]
      wl4[tid * 35 + (((g - 11) >> 2) - 32 * c)] = pack;
  }
  __syncthreads();
  // out write: per instr, 2 channels x 512B contiguous (32 lanes x float4 each)
  float4* outq = reinterpret_cast<float4*>(out);
#pragma unroll
  for (int i = 0; i < 32; ++i) {
    int idx = tid + i * 256;            // 0..8191 = 256 ch x 32 float4-cols
    int ch  = idx >> 5;
    int f4  = idx & 31;
    outq[(size_t)(blockIdx.y * 256 + ch) * 4096 + 32 * c + f4] = wl4[ch * 35 + f4];
  }
}

// ---------------- host: exact cheby1/zi design in double ----------------------
static void solve8(double Mm[8][9], double* zi) {
  for (int col = 0; col < 8; ++col) {
    int piv = col;
    for (int r = col + 1; r < 8; ++r)
      if (std::fabs(Mm[r][col]) > std::fabs(Mm[piv][col])) piv = r;
    if (piv != col)
      for (int j = 0; j < 9; ++j) { double t = Mm[col][j]; Mm[col][j] = Mm[piv][j]; Mm[piv][j] = t; }
    double d = Mm[col][col];
    for (int j = col; j < 9; ++j) Mm[col][j] /= d;
    for (int r = 0; r < 8; ++r)
      if (r != col) {
        double f = Mm[r][col];
        if (f != 0.0)
          for (int j = col; j < 9; ++j) Mm[r][j] -= f * Mm[col][j];
      }
  }
  for (int i = 0; i < 8; ++i) zi[i] = Mm[i][8];
}

static Coefs make_coefs() {
  using cd = std::complex<double>;
  const int N = 8;
  const double rp = 0.05, Wn = 0.8 / 4.0;
  double eps = std::sqrt(std::pow(10.0, 0.1 * rp) - 1.0);
  double mu = std::asinh(1.0 / eps) / N;
  cd p[8];
  for (int i = 0; i < N; ++i) {
    double th = M_PI * (2.0 * (i + 1) - 1.0) / (2.0 * N);
    p[i] = cd(-std::sinh(mu) * std::sin(th), std::cosh(mu) * std::cos(th));
  }
  cd pr(1.0, 0.0);
  for (int i = 0; i < N; ++i) pr *= -p[i];
  double g = pr.real();
  g /= std::sqrt(1.0 + eps * eps);                 // N even
  const double fs = 2.0;
  double warped = 2.0 * fs * std::tan(M_PI * Wn / fs);
  for (int i = 0; i < N; ++i) p[i] *= warped;
  g *= std::pow(warped, (double)N);
  const double fs2 = 2.0 * fs;
  cd pd[8], dpr(1.0, 0.0);
  for (int i = 0; i < N; ++i) {
    pd[i] = (cd(fs2, 0.0) + p[i]) / (cd(fs2, 0.0) - p[i]);
    dpr *= (cd(fs2, 0.0) - p[i]);
  }
  double gd = g * (cd(1.0, 0.0) / dpr).real();
  static const double binom[9] = {1, 8, 28, 56, 70, 56, 28, 8, 1};
  double b[9], a[9];
  for (int i = 0; i < 9; ++i) b[i] = gd * binom[i];
  cd cp[9]; cp[0] = cd(1, 0);
  for (int i = 1; i < 9; ++i) cp[i] = cd(0, 0);
  for (int i = 0; i < N; ++i)
    for (int j = i + 1; j >= 1; --j) cp[j] -= pd[i] * cp[j - 1];
  for (int i = 0; i < 9; ++i) a[i] = cp[i].real();
  double Mm[8][9];
  for (int i = 0; i < 8; ++i) {
    for (int j = 0; j < 9; ++j) Mm[i][j] = 0.0;
    Mm[i][0] += a[i + 1];
    Mm[i][i] += 1.0;
    if (i < 7) Mm[i][i + 1] = -1.0;
    Mm[i][8] = b[i + 1] - a[i + 1] * b[0];
  }
  double zi[8];
  solve8(Mm, zi);
  Coefs cf;
  cf.b0 = (float)b[0]; cf.b1 = (float)b[1]; cf.b2 = (float)b[2]; cf.b3 = (float)b[3];
  cf.b4 = (float)b[4]; cf.b5 = (float)b[5]; cf.b6 = (float)b[6]; cf.b7 = (float)b[7];
  cf.b8 = (float)b[8];
  cf.na1 = (float)(-a[1]); cf.na2 = (float)(-a[2]); cf.na3 = (float)(-a[3]);
  cf.na4 = (float)(-a[4]); cf.na5 = (float)(-a[5]); cf.na6 = (float)(-a[6]);
  cf.na7 = (float)(-a[7]); cf.na8 = (float)(-a[8]);
  cf.zi0 = (float)zi[0]; cf.zi1 = (float)zi[1]; cf.zi2 = (float)zi[2]; cf.zi3 = (float)zi[3];
  cf.zi4 = (float)zi[4]; cf.zi5 = (float)zi[5]; cf.zi6 = (float)zi[6]; cf.zi7 = (float)zi[7];
  return cf;
}

}  // namespace

extern "C" void kernel_launch(void* const* d_in, const int* in_sizes, int n_in,
                              void* d_out, int out_size, void* d_ws, size_t ws_size,
                              hipStream_t stream) {
  (void)in_sizes; (void)n_in; (void)out_size; (void)ws_size;
  const float* x = (const float*)d_in[0];
  float* out = (float*)d_out;
  float* yb  = (float*)d_ws;                       // 134.4 MB (round-0 layout)
  Coefs cf = make_coefs();                         // pure host math, capture-safe
  hipLaunchKernelGGL(k_fwd2, dim3(128, NCH / 64), dim3(256), 0, stream, x, yb, cf);
  hipLaunchKernelGGL(k_bwd3, dim3(128, 2), dim3(256), 0, stream, yb, out, cf);
}

// Round 7
// 290.043 us; speedup vs baseline: 1.0567x; 1.0567x over previous
//
#include <hip/hip_runtime.h>
#include <cmath>
#include <complex>

namespace {

constexpr int TLEN   = 65536;
constexpr int NCH    = 512;            // 32*16 channels
constexpr size_t YB_ROWS = 16400;      // float4-groups in yb (valid g <= 16398)

// yb layout (round-0, proven): sample e at row s=e+5, float offset
// (s>>2)*2048 + ch*4 + (s&3). 1KB-contiguous per (group, 64ch tile).

struct Coefs {
  float b0,b1,b2,b3,b4,b5,b6,b7,b8;
  float na1,na2,na3,na4,na5,na6,na7,na8;   // -a[1..8]
  float zi0,zi1,zi2,zi3,zi4,zi5,zi6,zi7;
};

#define IIR_STEP(xv, yv)                                  \
  do {                                                    \
    yv = fmaf(cf.b0, (xv), z0);                           \
    z0 = fmaf(cf.na1, yv, fmaf(cf.b1, (xv), z1));         \
    z1 = fmaf(cf.na2, yv, fmaf(cf.b2, (xv), z2));         \
    z2 = fmaf(cf.na3, yv, fmaf(cf.b3, (xv), z3));         \
    z3 = fmaf(cf.na4, yv, fmaf(cf.b4, (xv), z4));         \
    z4 = fmaf(cf.na5, yv, fmaf(cf.b5, (xv), z5));         \
    z5 = fmaf(cf.na6, yv, fmaf(cf.b6, (xv), z6));         \
    z6 = fmaf(cf.na7, yv, fmaf(cf.b7, (xv), z7));         \
    z7 = fmaf(cf.na8, yv, cf.b8 * (xv));                  \
  } while (0)

// =============== K1: fused extension+transpose+forward scan ==================
// Round-4 structure VERBATIM (proven: 112us, FETCH=110MB WRITE=131MB, Occ 22.4):
// 4-wave blocks, wave 0 scans, all waves stage, 2-ring LDS (33.3KB -> 4/CU),
// grid 129 x 8 with separate c=128 mini-chunk. Round-6's tail-merge +
// per-subtile interior test REGRESSED (+20us, VGPR 84->92, Occ -6pts) - reverted.
template<int QOFF, bool VEC>
__device__ __forceinline__ void run_chunk(const float* __restrict__ x,
                                          float* __restrict__ yb,
                                          const Coefs& cf,
                                          float (&lds)[2][4160],
                                          int m0, int e0, int nsub,
                                          int store_lo, int store_hi) {
  const int tid  = threadIdx.x;
  const int lane = tid & 63;
  const int vtbase = e0 - 27;            // x-index of e0
  const int mIdx = m0 + lane;
  float4* yq = reinterpret_cast<float4*>(yb);
  const int tq  = tid & 15;              // VEC: float4-column within row
  const int chb = tid >> 4;              // VEC: base channel row (0..15)
  float4 rr0, rr1, rr2, rr3;             // VEC staging
  float rs[16];                          // edge staging

  auto issue = [&](int k) {
    const int vt0 = vtbase + 64 * k;
    if (VEC) {
      const float* p = x + (size_t)(m0 + chb) * TLEN + vt0 + 4 * tq;
      rr0 = *reinterpret_cast<const float4*>(p);
      rr1 = *reinterpret_cast<const float4*>(p + (size_t)16 * TLEN);
      rr2 = *reinterpret_cast<const float4*>(p + (size_t)32 * TLEN);
      rr3 = *reinterpret_cast<const float4*>(p + (size_t)48 * TLEN);
    } else {
#pragma unroll
      for (int i = 0; i < 16; ++i) {
        int idx = tid + 256 * i;
        int tl = idx & 63, ch = idx >> 6;
        int vt = vt0 + tl;
        const float* xr = x + (size_t)(m0 + ch) * TLEN;
        float v;
        if (vt < 0) v = 2.0f * xr[0] - xr[-vt];
        else if (vt >= TLEN) v = 2.0f * xr[TLEN - 1] - xr[2 * TLEN - 2 - vt];
        else v = xr[vt];
        rs[i] = v;
      }
    }
  };
  auto commit = [&](int k) {
    float* b = lds[k & 1];
    if (VEC) {
      const int base = 4 * tq * 65;
      b[base       + chb     ] = rr0.x; b[base + 65  + chb     ] = rr0.y;
      b[base + 130 + chb     ] = rr0.z; b[base + 195 + chb     ] = rr0.w;
      b[base       + chb + 16] = rr1.x; b[base + 65  + chb + 16] = rr1.y;
      b[base + 130 + chb + 16] = rr1.z; b[base + 195 + chb + 16] = rr1.w;
      b[base       + chb + 32] = rr2.x; b[base + 65  + chb + 32] = rr2.y;
      b[base + 130 + chb + 32] = rr2.z; b[base + 195 + chb + 32] = rr2.w;
      b[base       + chb + 48] = rr3.x; b[base + 65  + chb + 48] = rr3.y;
      b[base + 130 + chb + 48] = rr3.z; b[base + 195 + chb + 48] = rr3.w;
    } else {
#pragma unroll
      for (int i = 0; i < 16; ++i) {
        int idx = tid + 256 * i;
        int tl = idx & 63, ch = idx >> 6;
        b[tl * 65 + ch] = rs[i];
      }
    }
  };

  // prologue: subtile 0 only (2-ring, depth 1)
  issue(0); commit(0);

  float z0 = 0, z1 = 0, z2 = 0, z3 = 0, z4 = 0, z5 = 0, z6 = 0, z7 = 0;
  float4 oq = make_float4(0.f, 0.f, 0.f, 0.f);

  for (int k = 0; k < nsub; ++k) {
    if (k + 1 < nsub) issue(k + 1);      // loads in flight across the barrier
    __syncthreads();                     // buf k&1 committed (end of iter k-1)
    if (k == 0 && tid < 64) {
      float x0 = lds[0][lane];           // x_ext(e0)
      z0 = cf.zi0 * x0; z1 = cf.zi1 * x0; z2 = cf.zi2 * x0; z3 = cf.zi3 * x0;
      z4 = cf.zi4 * x0; z5 = cf.zi5 * x0; z6 = cf.zi6 * x0; z7 = cf.zi7 * x0;
    }
    if (tid < 64) {
      const float* tile = lds[k & 1];
#pragma unroll
      for (int tl = 0; tl < 64; ++tl) {
        float xin = tile[tl * 65 + lane];
        float yv; IIR_STEP(xin, yv);
        if (QOFF == 1) {                   // c==0 scalar head e=0,1,2 (grp1 q1..3)
          if (k == 0 && tl < 3) yb[2048 + mIdx * 4 + tl + 1] = yv;
        }
        const int q = (tl + QOFF) & 3;     // q = (e+1)&3, static after unroll
        if (q == 0) oq.x = yv;
        else if (q == 1) oq.y = yv;
        else if (q == 2) oq.z = yv;
        else {
          oq.w = yv;
          const int step = 64 * k + tl;
          if (step >= store_lo && step <= store_hi)
            yq[(size_t)((e0 + step + 5) >> 2) * 512 + mIdx] = oq;
        }
      }
    }
    if (k + 1 < nsub) commit(k + 1);     // writes buf (k+1)&1 (scan reads k&1)
  }
}

__global__ __launch_bounds__(256) void k_fwd2(const float* __restrict__ x,
                                              float* __restrict__ yb, Coefs cf) {
  __shared__ float lds[2][4160];           // 33.3 KB -> 4 blocks/CU
  const int c  = blockIdx.x;               // chunk 0..128
  const int m0 = blockIdx.y * 64;          // channel tile
  if (c == 0)
    run_chunk<1, false>(x, yb, cf, lds, m0, 0, 8, 6, 510);
  else if (c == 128)
    run_chunk<0, false>(x, yb, cf, lds, m0, 65283, 5, 255, 307);
  else
    run_chunk<0, true>(x, yb, cf, lds, m0, 512 * c - 253, 12, 255, 763);
}

// ---------------- K2: backward chunked scan -> out, fused transpose ----------
// bwd3 geometry unchanged (128 chunks x 2 halves, 1 block/CU at 143KB LDS,
// warm-up 272, c==127 exact zi-init). Round-7 edit: prefetch depth 3 -> 4
// (b0..b15, issue ld(g-16..g-19)) - probes whether bwd is latency-limited at
// 4 waves/CU (expect -15..30us) or pattern-BW-bound (expect null).
__global__ __launch_bounds__(256) void k_bwd3(const float* __restrict__ yb,
                                              float* __restrict__ out, Coefs cf) {
  __shared__ float4 wl4[256 * 35];       // [ch][32 col-quads], pitch 35 -> 143.4KB
  const int c   = blockIdx.x;            // 0..127
  const int tid = threadIdx.x;
  const int m   = blockIdx.y * 256 + tid;
  float z0, z1, z2, z3, z4, z5, z6, z7;
  int g_begin;
  if (c == 127) {                        // exact filtfilt backward init
    float y0 = yb[(size_t)16398 * 2048 + (size_t)m * 4 + 2];   // s=65594 (u=0)
    z0 = cf.zi0 * y0; z1 = cf.zi1 * y0; z2 = cf.zi2 * y0; z3 = cf.zi3 * y0;
    z4 = cf.zi4 * y0; z5 = cf.zi5 * y0; z6 = cf.zi6 * y0; z7 = cf.zi7 * y0;
#pragma unroll
    for (int s = 65594; s >= 65584; --s) {       // u = 0..10 (no owned outputs)
      float yin = yb[(size_t)(s >> 2) * 2048 + (size_t)m * 4 + (s & 3)];
      float wv; IIR_STEP(yin, wv);
      (void)wv;
    }
    g_begin = 16395;
  } else {
    g_begin = 128 * c + 203;                     // warm-up init at q3 of g_begin
    float y0 = yb[(size_t)g_begin * 2048 + (size_t)m * 4 + 3];
    z0 = cf.zi0 * y0; z1 = cf.zi1 * y0; z2 = cf.zi2 * y0; z3 = cf.zi3 * y0;
    z4 = cf.zi4 * y0; z5 = cf.zi5 * y0; z6 = cf.zi6 * y0; z7 = cf.zi7 * y0;
  }
  const int g_stop = 128 * c + 11;       // last pack: col-base 128c
  const int g_hi   = 128 * c + 135;      // first owned pack (c=127: 16391)
  const float4* yv = reinterpret_cast<const float4*>(yb);
  auto ld = [&](int r) {
    int rr = r < 0 ? 0 : r;
    return yv[(size_t)rr * 512 + m];
  };
  float4 b0  = ld(g_begin),      b1  = ld(g_begin - 1),  b2  = ld(g_begin - 2),  b3  = ld(g_begin - 3);
  float4 b4  = ld(g_begin - 4),  b5  = ld(g_begin - 5),  b6  = ld(g_begin - 6),  b7  = ld(g_begin - 7);
  float4 b8  = ld(g_begin - 8),  b9  = ld(g_begin - 9),  b10 = ld(g_begin - 10), b11 = ld(g_begin - 11);
  float4 b12 = ld(g_begin - 12), b13 = ld(g_begin - 13), b14 = ld(g_begin - 14), b15 = ld(g_begin - 15);
  for (int g = g_begin; g >= g_stop; g -= 4) {
    float4 c0 = b0, c1 = b1, c2 = b2, c3 = b3;
    b0 = b4;  b1 = b5;  b2 = b6;  b3 = b7;
    b4 = b8;  b5 = b9;  b6 = b10; b7 = b11;
    b8 = b12; b9 = b13; b10 = b14; b11 = b15;
    b12 = ld(g - 16); b13 = ld(g - 17); b14 = ld(g - 18); b15 = ld(g - 19);
    float4 pack;
#pragma unroll
    for (int j = 0; j < 4; ++j) {
      float4 q = (j == 0) ? c0 : (j == 1) ? c1 : (j == 2) ? c2 : c3;
      float w3, w2, w1, w0;
      IIR_STEP(q.w, w3);   // ascending u within group: q3,q2,q1,q0
      IIR_STEP(q.z, w2);
      IIR_STEP(q.y, w1);
      IIR_STEP(q.x, w0);
      (void)w3; (void)w2; (void)w1;
      if (j == 0) pack.w = w0;          // col g-8
      else if (j == 1) pack.z = w0;     // col g-9
      else if (j == 2) pack.y = w0;     // col g-10
      else pack.x = w0;                 // col g-11
    }
    if (g <= g_hi)                      // owned packs: col-base (g-11) in [128c, 128c+124]
      wl4[tid * 35 + (((g - 11) >> 2) - 32 * c)] = pack;
  }
  __syncthreads();
  // out write: per instr, 2 channels x 512B contiguous (32 lanes x float4 each)
  float4* outq = reinterpret_cast<float4*>(out);
#pragma unroll
  for (int i = 0; i < 32; ++i) {
    int idx = tid + i * 256;            // 0..8191 = 256 ch x 32 float4-cols
    int ch  = idx >> 5;
    int f4  = idx & 31;
    outq[(size_t)(blockIdx.y * 256 + ch) * 4096 + 32 * c + f4] = wl4[ch * 35 + f4];
  }
}

// ---------------- host: exact cheby1/zi design in double ----------------------
static void solve8(double Mm[8][9], double* zi) {
  for (int col = 0; col < 8; ++col) {
    int piv = col;
    for (int r = col + 1; r < 8; ++r)
      if (std::fabs(Mm[r][col]) > std::fabs(Mm[piv][col])) piv = r;
    if (piv != col)
      for (int j = 0; j < 9; ++j) { double t = Mm[col][j]; Mm[col][j] = Mm[piv][j]; Mm[piv][j] = t; }
    double d = Mm[col][col];
    for (int j = col; j < 9; ++j) Mm[col][j] /= d;
    for (int r = 0; r < 8; ++r)
      if (r != col) {
        double f = Mm[r][col];
        if (f != 0.0)
          for (int j = col; j < 9; ++j) Mm[r][j] -= f * Mm[col][j];
      }
  }
  for (int i = 0; i < 8; ++i) zi[i] = Mm[i][8];
}

static Coefs make_coefs() {
  using cd = std::complex<double>;
  const int N = 8;
  const double rp = 0.05, Wn = 0.8 / 4.0;
  double eps = std::sqrt(std::pow(10.0, 0.1 * rp) - 1.0);
  double mu = std::asinh(1.0 / eps) / N;
  cd p[8];
  for (int i = 0; i < N; ++i) {
    double th = M_PI * (2.0 * (i + 1) - 1.0) / (2.0 * N);
    p[i] = cd(-std::sinh(mu) * std::sin(th), std::cosh(mu) * std::cos(th));
  }
  cd pr(1.0, 0.0);
  for (int i = 0; i < N; ++i) pr *= -p[i];
  double g = pr.real();
  g /= std::sqrt(1.0 + eps * eps);                 // N even
  const double fs = 2.0;
  double warped = 2.0 * fs * std::tan(M_PI * Wn / fs);
  for (int i = 0; i < N; ++i) p[i] *= warped;
  g *= std::pow(warped, (double)N);
  const double fs2 = 2.0 * fs;
  cd pd[8], dpr(1.0, 0.0);
  for (int i = 0; i < N; ++i) {
    pd[i] = (cd(fs2, 0.0) + p[i]) / (cd(fs2, 0.0) - p[i]);
    dpr *= (cd(fs2, 0.0) - p[i]);
  }
  double gd = g * (cd(1.0, 0.0) / dpr).real();
  static const double binom[9] = {1, 8, 28, 56, 70, 56, 28, 8, 1};
  double b[9], a[9];
  for (int i = 0; i < 9; ++i) b[i] = gd * binom[i];
  cd cp[9]; cp[0] = cd(1, 0);
  for (int i = 1; i < 9; ++i) cp[i] = cd(0, 0);
  for (int i = 0; i < N; ++i)
    for (int j = i + 1; j >= 1; --j) cp[j] -= pd[i] * cp[j - 1];
  for (int i = 0; i < 9; ++i) a[i] = cp[i].real();
  double Mm[8][9];
  for (int i = 0; i < 8; ++i) {
    for (int j = 0; j < 9; ++j) Mm[i][j] = 0.0;
    Mm[i][0] += a[i + 1];
    Mm[i][i] += 1.0;
    if (i < 7) Mm[i][i + 1] = -1.0;
    Mm[i][8] = b[i + 1] - a[i + 1] * b[0];
  }
  double zi[8];
  solve8(Mm, zi);
  Coefs cf;
  cf.b0 = (float)b[0]; cf.b1 = (float)b[1]; cf.b2 = (float)b[2]; cf.b3 = (float)b[3];
  cf.b4 = (float)b[4]; cf.b5 = (float)b[5]; cf.b6 = (float)b[6]; cf.b7 = (float)b[7];
  cf.b8 = (float)b[8];
  cf.na1 = (float)(-a[1]); cf.na2 = (float)(-a[2]); cf.na3 = (float)(-a[3]);
  cf.na4 = (float)(-a[4]); cf.na5 = (float)(-a[5]); cf.na6 = (float)(-a[6]);
  cf.na7 = (float)(-a[7]); cf.na8 = (float)(-a[8]);
  cf.zi0 = (float)zi[0]; cf.zi1 = (float)zi[1]; cf.zi2 = (float)zi[2]; cf.zi3 = (float)zi[3];
  cf.zi4 = (float)zi[4]; cf.zi5 = (float)zi[5]; cf.zi6 = (float)zi[6]; cf.zi7 = (float)zi[7];
  return cf;
}

}  // namespace

extern "C" void kernel_launch(void* const* d_in, const int* in_sizes, int n_in,
                              void* d_out, int out_size, void* d_ws, size_t ws_size,
                              hipStream_t stream) {
  (void)in_sizes; (void)n_in; (void)out_size; (void)ws_size;
  const float* x = (const float*)d_in[0];
  float* out = (float*)d_out;
  float* yb  = (float*)d_ws;                       // 134.4 MB (round-0 layout)
  Coefs cf = make_coefs();                         // pure host math, capture-safe
  hipLaunchKernelGGL(k_fwd2, dim3(129, NCH / 64), dim3(256), 0, stream, x, yb, cf);
  hipLaunchKernelGGL(k_bwd3, dim3(128, 2), dim3(256), 0, stream, yb, out, cf);
}